// Round 15
// baseline (165.952 us; speedup 1.0000x reference)
//
#include <hip/hip_runtime.h>
#include <hip/hip_bf16.h>
#include <cstdint>
#include <cstddef>

// B=8192, CIN=16, 6x6->5x5 (k=2 VALID), FM=64, DK=DV=NH=32 (dkh=1), HID=128, OUT=5.
// R15 = R14 phases (packed-fp32 attention, zero barriers) with 2 BATCHES PER WAVE,
// software-pipelined: batch-B x-loads issued before phase2(A) so HBM latency hides
// under the exp burst; prologue (B-frags/bias/wab) amortized over 2 batches.
// act layout [b][pos][ch] (dense K-permuted); w1bp pre-permuted to match.

typedef __attribute__((ext_vector_type(4))) float f32x4;
typedef __attribute__((ext_vector_type(2))) float f32x2;
typedef __attribute__((ext_vector_type(8))) __bf16 bf16x8;
typedef __attribute__((ext_vector_type(4))) __bf16 bf16x4;

#define LOG2E 1.4426950408889634f

// raw v_exp_f32 (2^x) — exp2f() lowers to the OCML wrapper (~4 extra VALU ops),
// measured as the R4->R6 attention regression (R7 confirmed the fix: -20us).
__device__ __forceinline__ float fast_exp2(float x) {
#if __has_builtin(__builtin_amdgcn_exp2f)
  return __builtin_amdgcn_exp2f(x);
#else
  return __expf(x * 0.6931471805599453f);
#endif
}

// v_mfma_f32_16x16x32_bf16 (bench-verified layout R2-R14):
// A: lane holds A[m=lane&15][k=quad*8+j]; B: W[n=lane&15][k=quad*8+j];
// C/D: col=lane&15, row=quad*4+reg.
__device__ __forceinline__ f32x4 mfma16(bf16x8 a, bf16x8 b, f32x4 c) {
  return __builtin_amdgcn_mfma_f32_16x16x32_bf16(a, b, c, 0, 0, 0);
}

// ---------------- prep_small: ONLY what k1's main blocks read (unchanged) ----------------
__global__ __launch_bounds__(64) void prep_small(
    const float* __restrict__ conv_w, const float* __restrict__ conv_b,
    const float* __restrict__ qkv_w,  const float* __restrict__ qkv_b,
    const float* __restrict__ attn_w,
    __hip_bfloat16* __restrict__ wqb, float* __restrict__ biasb,
    __hip_bfloat16* __restrict__ wab) {
  const int t = threadIdx.x, tb = blockIdx.x;
  if (tb < 16) {
#pragma unroll
    for (int j = 0; j < 8; ++j) {
      int i = tb * 512 + j * 64 + t;
      float w = (i < 2048) ? conv_w[i] : qkv_w[i - 2048];
      if (i >= 4096 && i < 6144) w *= LOG2E;  // k-channel rows 64..95
      wqb[i] = __float2bfloat16(w);
    }
  } else {
#pragma unroll
    for (int j = 0; j < 16; ++j) wab[j * 64 + t] = __float2bfloat16(attn_w[j * 64 + t]);
    for (int i = t; i < 128; i += 64) {
      float b = (i < 32) ? conv_b[i] : qkv_b[i - 32];
      if (i >= 64 && i < 96) b *= LOG2E;
      biasb[i] = b;
    }
  }
}

// ---- per-wave phase helpers (R14 code, parameterized by batch + LDS ptrs) ----

struct WaveCtx {
  int t, l15, quad;
  bf16x8 bfr[8][2];
  float bias[8];
  bf16x8 bw[2];
  float ab[2];
};

__device__ __forceinline__ void phase1(
    const WaveCtx& c, int b, const __bf16* xs, __bf16* qs,
    __hip_bfloat16* __restrict__ act) {
#pragma unroll
  for (int mt = 0; mt < 2; ++mt) {
    int row = mt * 16 + c.l15;
    int pos = row < 24 ? row : 24;
    int ii = pos / 5, jj = pos - ii * 5;
    const __bf16* xp = xs + ii * 6 + jj;
    bf16x8 af[2];
#pragma unroll
    for (int ks = 0; ks < 2; ++ks) {
      const __bf16* p0 = xp + (ks * 8 + c.quad * 2) * 36;
      bf16x8 a;
      a[0] = p0[0];  a[1] = p0[1];  a[2] = p0[6];  a[3] = p0[7];
      a[4] = p0[36]; a[5] = p0[37]; a[6] = p0[42]; a[7] = p0[43];
      af[ks] = a;
    }
    f32x4 acc[8];
#pragma unroll
    for (int nt = 0; nt < 8; ++nt) acc[nt] = (f32x4){0.f, 0.f, 0.f, 0.f};
#pragma unroll
    for (int ks = 0; ks < 2; ++ks)
#pragma unroll
      for (int nt = 0; nt < 8; ++nt)
        acc[nt] = mfma16(af[ks], c.bfr[nt][ks], acc[nt]);

#pragma unroll
    for (int r = 0; r < 4; ++r) {
      int orow = mt * 16 + c.quad * 4 + r;
      if (orow < 25) {
#pragma unroll
        for (int nt = 0; nt < 8; ++nt) {
          float v = acc[nt][r] + c.bias[nt];
          if (nt < 2) {  // conv_out ch 0..31 -> global with relu
            act[((size_t)b * 25 + orow) * 64 + nt * 16 + c.l15] =
                __float2bfloat16(fmaxf(v, 0.f));
          } else {       // qkv ch 0..95 -> LDS (k already log2e-scaled via weights)
            qs[((nt - 2) * 16 + c.l15) * 28 + orow] = __float2bfloat16(v);
          }
        }
      }
    }
  }
}

__device__ __forceinline__ void phase2(const WaveCtx& c, const __bf16* qs, __bf16* as_) {
  const int n = c.t & 31, half = c.t >> 5;
  const __bf16* qp = qs + n * 28;
  const __bf16* kp = qs + (32 + n) * 28;
  const __bf16* vp = qs + (64 + n) * 28;
  f32x2 kl2[12], vv2[12];
  float kl24, vv24;
#pragma unroll
  for (int c4 = 0; c4 < 6; ++c4) {
    bf16x4 bb = *(const bf16x4*)(kp + c4 * 4);
    bf16x4 cc = *(const bf16x4*)(vp + c4 * 4);
    kl2[c4 * 2]     = (f32x2){(float)bb[0], (float)bb[1]};
    kl2[c4 * 2 + 1] = (f32x2){(float)bb[2], (float)bb[3]};
    vv2[c4 * 2]     = (f32x2){(float)cc[0], (float)cc[1]};
    vv2[c4 * 2 + 1] = (f32x2){(float)cc[2], (float)cc[3]};
  }
  kl24 = (float)kp[24]; vv24 = (float)vp[24];

  const int i0 = half * 12;
  float qv[13];
  {
    const __bf16* qbase = qp + i0;  // row*56 + i0*2: 8B-aligned for i0 in {0,12}
    bf16x4 q0 = *(const bf16x4*)(qbase);
    bf16x4 q1 = *(const bf16x4*)(qbase + 4);
    bf16x4 q2 = *(const bf16x4*)(qbase + 8);
#pragma unroll
    for (int z = 0; z < 4; ++z) {
      qv[z] = (float)q0[z]; qv[4 + z] = (float)q1[z]; qv[8 + z] = (float)q2[z];
    }
    qv[12] = (float)qbase[12];
  }

#pragma unroll
  for (int z = 0; z < 13; ++z) {
    const float qi = qv[z];
    const f32x2 qi2 = {qi, qi};
    f32x2 sA = {0.f, 0.f}, sB = {0.f, 0.f};
    f32x2 oA = {0.f, 0.f}, oB = {0.f, 0.f};
    float s4 = 0.f, o4 = 0.f;
#pragma unroll
    for (int p = 0; p < 6; ++p) {
      f32x2 mA = qi2 * kl2[p];          // v_pk_mul_f32
      f32x2 mB = qi2 * kl2[p + 6];
      f32x2 eA = {fast_exp2(mA.x), fast_exp2(mA.y)};
      f32x2 eB = {fast_exp2(mB.x), fast_exp2(mB.y)};
      sA += eA;                          // v_pk_add_f32
      sB += eB;
      oA = eA * vv2[p] + oA;             // v_pk_fma_f32
      oB = eB * vv2[p + 6] + oB;
    }
    {
      float e = fast_exp2(qi * kl24);
      s4 += e;
      o4 = __builtin_fmaf(e, vv24, o4);
    }
    float ss = ((sA.x + sA.y) + (sB.x + sB.y)) + s4;
    float oo = ((oA.x + oA.y) + (oB.x + oB.y)) + o4;
    as_[(i0 + z) * 32 + n] = __float2bfloat16(oo * __builtin_amdgcn_rcpf(ss));
  }
}

__device__ __forceinline__ void phase3(
    const WaveCtx& c, int b, const __bf16* as_, __hip_bfloat16* __restrict__ act) {
#pragma unroll
  for (int mt = 0; mt < 2; ++mt) {
    int row = mt * 16 + c.l15;
    int rc = row < 24 ? row : 24;
    bf16x8 af = *(const bf16x8*)(as_ + rc * 32 + c.quad * 8);
    f32x4 acc[2];
#pragma unroll
    for (int nt2 = 0; nt2 < 2; ++nt2)
      acc[nt2] = mfma16(af, c.bw[nt2], (f32x4){0.f, 0.f, 0.f, 0.f});
#pragma unroll
    for (int r = 0; r < 4; ++r) {
      int orow = mt * 16 + c.quad * 4 + r;
      if (orow < 25) {
#pragma unroll
        for (int nt2 = 0; nt2 < 2; ++nt2)
          act[((size_t)b * 25 + orow) * 64 + 32 + nt2 * 16 + c.l15] =
              __float2bfloat16(fmaxf(acc[nt2][r] + c.ab[nt2], 0.f));
      }
    }
  }
}

// ---------------- k1: fused conv+qkv GEMM + attention + 1x1 conv ----------------
// Main blocks 0..2047: 2 waves x 2 batches each (software-pipelined), private LDS,
// no barriers. Tail blocks 2048..2113: 2 waves x 1 prep unit (w1bp / w2b).
// Per-wave LDS (8192 B): RA[0,1600) = xsA / as_;  qs[1600,6976);  xsB[6976,8128).
__global__ __launch_bounds__(128) void k1(
    const float* __restrict__ x,
    const float* __restrict__ biasb,
    const __hip_bfloat16* __restrict__ wqb,
    const __hip_bfloat16* __restrict__ wab, const float* __restrict__ attn_b,
    const float* __restrict__ w1, const float* __restrict__ w2,
    __hip_bfloat16* __restrict__ act,
    __hip_bfloat16* __restrict__ w1bp, __hip_bfloat16* __restrict__ w2b) {
  const int t = threadIdx.x & 63;   // lane within wave
  const int wv = threadIdx.x >> 6;  // wave 0/1 in block

  __shared__ __align__(16) char lds_raw[2 * 8192];
  char* my = lds_raw + wv * 8192;   // private per-wave region

  // ---- tail blocks: k2-input prep (runs in main-grid drain shadow) ----
  if (blockIdx.x >= 2048) {
    const int u = (blockIdx.x - 2048) * 2 + wv;  // unit 0..131
    if (u < 128) {
      float* rowf = (float*)my;  // 6400 B <= 8192 OK
      const float* wr = w1 + u * 1600;
#pragma unroll
      for (int j = 0; j < 25; ++j) rowf[j * 64 + t] = wr[j * 64 + t];
      __hip_bfloat16* wo = w1bp + u * 1600;
#pragma unroll
      for (int j = 0; j < 25; ++j) {
        // read lds[t*25+j]: stride-25 dwords, gcd(25,32)=1 -> conflict-free
        wo[j * 64 + t] = __float2bfloat16(rowf[t * 25 + j]);
      }
    } else if (u < 132) {  // w2b cast (2048 each, coalesced)
#pragma unroll
      for (int j = 0; j < 32; ++j) {
        int i = (u - 128) * 2048 + j * 64 + t;
        w2b[i] = __float2bfloat16(w2[i]);
      }
    }
    return;
  }

  // ================= main path: 2 batches per wave =================
  WaveCtx c;
  c.t = t; c.l15 = t & 15; c.quad = t >> 4;
  const int w = blockIdx.x * 2 + wv;   // wave id 0..4095
  const int bA = w * 2, bB = w * 2 + 1;

  __bf16* ra  = (__bf16*)my;           // xsA, then as_ (phase2/3)
  __bf16* qs  = (__bf16*)(my + 1600);  // q:0-31 k:32-63(x log2e) v:64-95, stride 28
  __bf16* xsB = (__bf16*)(my + 6976);  // batch-B x staging

  // ---- stage x(A) -> bf16 LDS ----
  const float* xbA = x + (size_t)bA * 576;
#pragma unroll
  for (int i = 0; i < 9; ++i) {
    int f = t + i * 64;
    ra[f] = __float2bfloat16(xbA[f]);
  }

  // ---- prologue loads amortized over both batches ----
#pragma unroll
  for (int nt = 0; nt < 8; ++nt)
#pragma unroll
    for (int ks = 0; ks < 2; ++ks)
      c.bfr[nt][ks] = *(const bf16x8*)((const __bf16*)wqb + (nt * 16 + c.l15) * 64 + ks * 32 + c.quad * 8);
#pragma unroll
  for (int nt = 0; nt < 8; ++nt) c.bias[nt] = biasb[nt * 16 + c.l15];
#pragma unroll
  for (int nt2 = 0; nt2 < 2; ++nt2) {
    int n = nt2 * 16 + c.l15;
    c.bw[nt2] = *(const bf16x8*)((const __bf16*)wab + n * 32 + c.quad * 8);
    c.ab[nt2] = attn_b[n];
  }

  // ---- batch A: phase 1 ----
  phase1(c, bA, ra, qs, act);

  // ---- issue x(B) global loads now; latency hides under phase2(A)'s exp burst ----
  float xf[9];
  const float* xbB = x + (size_t)bB * 576;
#pragma unroll
  for (int i = 0; i < 9; ++i) xf[i] = xbB[t + i * 64];

  // ---- batch A: phase 2 (long exp burst) ----
  phase2(c, qs, ra);  // as_ aliases RA (xsA dead)

  // ---- drain x(B) into LDS (regs -> bf16 -> xsB) ----
#pragma unroll
  for (int i = 0; i < 9; ++i) xsB[t + i * 64] = __float2bfloat16(xf[i]);

  // ---- batch A: phase 3 ----
  phase3(c, bA, ra, act);

  // ---- batch B: phases 1-3 (qs reusable: phase2(A) reads complete in program order) ----
  phase1(c, bB, xsB, qs, act);
  phase2(c, qs, ra);
  phase3(c, bB, ra, act);
}

// ---------------- k2: fused dense chain — R2-proven 32-row/2-acc shape (unchanged) ----------------
__global__ __launch_bounds__(512) void k2(
    const __hip_bfloat16* __restrict__ act,
    const __hip_bfloat16* __restrict__ w1bp, const float* __restrict__ b1,
    const __hip_bfloat16* __restrict__ w2b, const float* __restrict__ b2,
    const float* __restrict__ w3, const float* __restrict__ b3,
    float* __restrict__ out) {
  const int t = threadIdx.x;
  const int lane = t & 63;
  const int wave = t >> 6;   // 0..7
  const int wm = wave >> 2;  // 0..1
  const int wn = wave & 3;   // 0..3
  const int l15 = lane & 15;
  const int quad = lane >> 4;  // 0..3
  const int b0 = blockIdx.x * 32;

  __shared__ __hip_bfloat16 C1s[32 * 136];
  __shared__ __hip_bfloat16 C2s[32 * 72];

  // ---- layer 1: [32,1600] x [128,1600]^T ----
  f32x4 acc0 = {0.f, 0.f, 0.f, 0.f};
  f32x4 acc1 = {0.f, 0.f, 0.f, 0.f};
  const __bf16* aptr  = (const __bf16*)act + (size_t)(b0 + wm * 16 + l15) * 1600 + quad * 8;
  const __bf16* bptr0 = (const __bf16*)w1bp + (size_t)(wn * 32 + l15) * 1600 + quad * 8;
  const __bf16* bptr1 = bptr0 + 16 * 1600;
#pragma unroll 5
  for (int k0 = 0; k0 < 1600; k0 += 32) {
    bf16x8 av  = *(const bf16x8*)(aptr + k0);
    bf16x8 bv0 = *(const bf16x8*)(bptr0 + k0);
    bf16x8 bv1 = *(const bf16x8*)(bptr1 + k0);
    acc0 = mfma16(av, bv0, acc0);
    acc1 = mfma16(av, bv1, acc1);
  }
  {
    const int col0 = wn * 32 + l15;
    const float bias0 = b1[col0];
    const float bias1 = b1[col0 + 16];
#pragma unroll
    for (int r = 0; r < 4; ++r) {
      const int row = wm * 16 + quad * 4 + r;
      C1s[row * 136 + col0]      = __float2bfloat16(fmaxf(acc0[r] + bias0, 0.f));
      C1s[row * 136 + col0 + 16] = __float2bfloat16(fmaxf(acc1[r] + bias1, 0.f));
    }
  }
  __syncthreads();

  // ---- layer 2: [32,128] x [64,128]^T ----
  f32x4 acc2 = {0.f, 0.f, 0.f, 0.f};
  {
    const __bf16* aL = (const __bf16*)C1s + (wm * 16 + l15) * 136 + quad * 8;
    const __bf16* bL = (const __bf16*)w2b + (wn * 16 + l15) * 128 + quad * 8;
#pragma unroll
    for (int k0 = 0; k0 < 128; k0 += 32)
      acc2 = mfma16(*(const bf16x8*)(aL + k0), *(const bf16x8*)(bL + k0), acc2);
  }
  {
    const int col = wn * 16 + l15;
    const float bias = b2[col];
#pragma unroll
    for (int r = 0; r < 4; ++r) {
      const int row = wm * 16 + quad * 4 + r;
      C2s[row * 72 + col] = __float2bfloat16(fmaxf(acc2[r] + bias, 0.f));
    }
  }
  __syncthreads();

  // ---- layer 3 (scalar, 160 outputs) ----
  if (t < 160) {
    const int row = t / 5;
    const int oc = t - row * 5;
    float s = b3[oc];
#pragma unroll
    for (int k = 0; k < 64; ++k)
      s += __bfloat162float(C2s[row * 72 + k]) * w3[oc * 64 + k];
    out[(size_t)(b0 + row) * 5 + oc] = s;
  }
}

extern "C" void kernel_launch(void* const* d_in, const int* in_sizes, int n_in,
                              void* d_out, int out_size, void* d_ws, size_t ws_size,
                              hipStream_t stream) {
  const float* x      = (const float*)d_in[0];
  const float* conv_w = (const float*)d_in[1];
  const float* conv_b = (const float*)d_in[2];
  const float* qkv_w  = (const float*)d_in[3];
  const float* qkv_b  = (const float*)d_in[4];
  const float* attn_w = (const float*)d_in[5];
  const float* attn_b = (const float*)d_in[6];
  const float* w1 = (const float*)d_in[7];
  const float* b1 = (const float*)d_in[8];
  const float* w2 = (const float*)d_in[9];
  const float* b2 = (const float*)d_in[10];
  const float* w3 = (const float*)d_in[11];
  const float* b3 = (const float*)d_in[12];
  float* out = (float*)d_out;

  // workspace layout (16B-aligned):
  //   act   [8192][25][64] bf16 : 26,214,400 B
  //   w1bp  [128][1600]    bf16 :    409,600 B  (written by k1 tail units 0..127)
  //   w2b   [64][128]      bf16 :     16,384 B  (written by k1 tail units 128..131)
  //   wqb   [128][64]      bf16 :     16,384 B  (k rows pre-scaled by log2e)
  //   biasb [128]          f32  :        512 B  (k entries pre-scaled by log2e)
  //   wab   [32][32]       bf16 :      2,048 B
  char* ws = (char*)d_ws;
  __hip_bfloat16* act   = (__hip_bfloat16*)ws;
  __hip_bfloat16* w1bp  = (__hip_bfloat16*)(ws + 26214400);
  __hip_bfloat16* w2b   = (__hip_bfloat16*)(ws + 26624000);
  __hip_bfloat16* wqb   = (__hip_bfloat16*)(ws + 26640384);
  float*          biasb = (float*)(ws + 26656768);
  __hip_bfloat16* wab   = (__hip_bfloat16*)(ws + 26657280);

  prep_small<<<dim3(17), dim3(64), 0, stream>>>(conv_w, conv_b, qkv_w, qkv_b, attn_w,
                                                wqb, biasb, wab);
  k1<<<dim3(2048 + 66), dim3(128), 0, stream>>>(x, biasb, wqb, wab, attn_b,
                                                w1, w2, act, w1bp, w2b);
  k2<<<dim3(256), dim3(512), 0, stream>>>(act, w1bp, b1, w2b, b2, w3, b3, out);
}

// Round 16
// 158.438 us; speedup vs baseline: 1.0474x; 1.0474x over previous
//
#include <hip/hip_runtime.h>
#include <hip/hip_bf16.h>
#include <cstdint>
#include <cstddef>

// B=8192, CIN=16, 6x6->5x5 (k=2 VALID), FM=64, DK=DV=NH=32 (dkh=1), HID=128, OUT=5.
// R16 = exact R14 revert (measured best: 158.8 us total, k1 44.3 us).
// k1: 2 waves/block, 1 batch/wave, private 7KB LDS regions, ZERO barriers,
//     packed-fp32 (v_pk_*) attention inner loop, raw v_exp_f32, log2e pre-scaled k.
// R15's 2-batch pipeline regressed (VGPR 76->128, occupancy 25->17%) — reverted.
// act layout [b][pos][ch] (dense K-permuted); w1bp pre-permuted to match.

typedef __attribute__((ext_vector_type(4))) float f32x4;
typedef __attribute__((ext_vector_type(2))) float f32x2;
typedef __attribute__((ext_vector_type(8))) __bf16 bf16x8;
typedef __attribute__((ext_vector_type(4))) __bf16 bf16x4;

#define LOG2E 1.4426950408889634f

// raw v_exp_f32 (2^x) — exp2f() lowers to the OCML wrapper (~4 extra VALU ops),
// measured as the R4->R6 attention regression (R7 confirmed the fix: -20us).
__device__ __forceinline__ float fast_exp2(float x) {
#if __has_builtin(__builtin_amdgcn_exp2f)
  return __builtin_amdgcn_exp2f(x);
#else
  return __expf(x * 0.6931471805599453f);
#endif
}

// v_mfma_f32_16x16x32_bf16 (bench-verified layout R2-R15):
// A: lane holds A[m=lane&15][k=quad*8+j]; B: W[n=lane&15][k=quad*8+j];
// C/D: col=lane&15, row=quad*4+reg.
__device__ __forceinline__ f32x4 mfma16(bf16x8 a, bf16x8 b, f32x4 c) {
  return __builtin_amdgcn_mfma_f32_16x16x32_bf16(a, b, c, 0, 0, 0);
}

// ---------------- prep_small: ONLY what k1's main blocks read ----------------
__global__ __launch_bounds__(64) void prep_small(
    const float* __restrict__ conv_w, const float* __restrict__ conv_b,
    const float* __restrict__ qkv_w,  const float* __restrict__ qkv_b,
    const float* __restrict__ attn_w,
    __hip_bfloat16* __restrict__ wqb, float* __restrict__ biasb,
    __hip_bfloat16* __restrict__ wab) {
  const int t = threadIdx.x, tb = blockIdx.x;
  if (tb < 16) {
#pragma unroll
    for (int j = 0; j < 8; ++j) {
      int i = tb * 512 + j * 64 + t;
      float w = (i < 2048) ? conv_w[i] : qkv_w[i - 2048];
      if (i >= 4096 && i < 6144) w *= LOG2E;  // k-channel rows 64..95
      wqb[i] = __float2bfloat16(w);
    }
  } else {
#pragma unroll
    for (int j = 0; j < 16; ++j) wab[j * 64 + t] = __float2bfloat16(attn_w[j * 64 + t]);
    for (int i = t; i < 128; i += 64) {
      float b = (i < 32) ? conv_b[i] : qkv_b[i - 32];
      if (i >= 64 && i < 96) b *= LOG2E;
      biasb[i] = b;
    }
  }
}

// ---------------- k1: fused conv+qkv GEMM + attention + 1x1 conv ----------------
// Main blocks 0..4095: 2 waves x 1 batch each, private LDS region, no barriers.
// Tail blocks 4096..4161: 2 waves x 1 prep unit each (w1bp rows / w2b cast).
__global__ __launch_bounds__(128) void k1(
    const float* __restrict__ x,
    const float* __restrict__ biasb,
    const __hip_bfloat16* __restrict__ wqb,
    const __hip_bfloat16* __restrict__ wab, const float* __restrict__ attn_b,
    const float* __restrict__ w1, const float* __restrict__ w2,
    __hip_bfloat16* __restrict__ act,
    __hip_bfloat16* __restrict__ w1bp, __hip_bfloat16* __restrict__ w2b) {
  const int t = threadIdx.x & 63;   // lane within wave
  const int wv = threadIdx.x >> 6;  // wave 0/1 in block

  __shared__ __align__(16) char lds_raw[2 * 7168];
  char* my = lds_raw + wv * 7168;   // private per-wave region

  // ---- tail blocks: k2-input prep (runs in main-grid drain shadow) ----
  if (blockIdx.x >= 4096) {
    const int u = (blockIdx.x - 4096) * 2 + wv;  // unit 0..131
    if (u < 128) {
      // w1bp row u: coalesced fp32 read -> LDS -> coalesced permuted bf16 write.
      float* rowf = (float*)my;  // 6400 B <= 7168 OK
      const float* wr = w1 + u * 1600;
#pragma unroll
      for (int j = 0; j < 25; ++j) rowf[j * 64 + t] = wr[j * 64 + t];
      // single wave: same-wave LDS RAW ordered by lgkmcnt (no barrier needed)
      __hip_bfloat16* wo = w1bp + u * 1600;
#pragma unroll
      for (int j = 0; j < 25; ++j) {
        // read lds[t*25+j]: stride-25 dwords, gcd(25,32)=1 -> conflict-free
        wo[j * 64 + t] = __float2bfloat16(rowf[t * 25 + j]);
      }
    } else if (u < 132) {  // w2b cast (2048 each, coalesced)
#pragma unroll
      for (int j = 0; j < 32; ++j) {
        int i = (u - 128) * 2048 + j * 64 + t;
        w2b[i] = __float2bfloat16(w2[i]);
      }
    }
    return;
  }

  // ================= main path =================
  const int l15 = t & 15, quad = t >> 4;
  const int b = blockIdx.x * 2 + wv;
  __bf16* xs  = (__bf16*)my;          // phase 1 (576 elems)
  __bf16* as_ = (__bf16*)my;          // phase 2/3 (800 elems, stride 32)
  __bf16* qs  = (__bf16*)(my + 1600); // q:0-31 k:32-63(x log2e) v:64-95, stride 28

  // ---- stage x -> bf16 LDS (576 floats, coalesced; same-wave ordering) ----
  const float* xb = x + (size_t)b * 576;
#pragma unroll
  for (int i = 0; i < 9; ++i) {
    int f = t + i * 64;
    xs[f] = __float2bfloat16(xb[f]);
  }

  // ---- B-frags from bf16 wqb (L2-hot 16KB) + pre-scaled biases ----
  bf16x8 bfr[8][2];
#pragma unroll
  for (int nt = 0; nt < 8; ++nt)
#pragma unroll
    for (int ks = 0; ks < 2; ++ks)
      bfr[nt][ks] = *(const bf16x8*)((const __bf16*)wqb + (nt * 16 + l15) * 64 + ks * 32 + quad * 8);
  float bias[8];
#pragma unroll
  for (int nt = 0; nt < 8; ++nt) bias[nt] = biasb[nt * 16 + l15];

  // ---- phase 1: implicit GEMM, M=25, N=128, K=64; 2 m-tiles sequential ----
#pragma unroll
  for (int mt = 0; mt < 2; ++mt) {
    int row = mt * 16 + l15;
    int pos = row < 24 ? row : 24;
    int ii = pos / 5, jj = pos - ii * 5;
    const __bf16* xp = xs + ii * 6 + jj;
    bf16x8 af[2];
#pragma unroll
    for (int ks = 0; ks < 2; ++ks) {
      const __bf16* p0 = xp + (ks * 8 + quad * 2) * 36;
      bf16x8 a;
      a[0] = p0[0];  a[1] = p0[1];  a[2] = p0[6];  a[3] = p0[7];
      a[4] = p0[36]; a[5] = p0[37]; a[6] = p0[42]; a[7] = p0[43];
      af[ks] = a;
    }
    f32x4 acc[8];
#pragma unroll
    for (int nt = 0; nt < 8; ++nt) acc[nt] = (f32x4){0.f, 0.f, 0.f, 0.f};
#pragma unroll
    for (int ks = 0; ks < 2; ++ks)
#pragma unroll
      for (int nt = 0; nt < 8; ++nt)
        acc[nt] = mfma16(af[ks], bfr[nt][ks], acc[nt]);

#pragma unroll
    for (int r = 0; r < 4; ++r) {
      int orow = mt * 16 + quad * 4 + r;
      if (orow < 25) {
#pragma unroll
        for (int nt = 0; nt < 8; ++nt) {
          float v = acc[nt][r] + bias[nt];
          if (nt < 2) {  // conv_out ch 0..31 -> global with relu
            act[((size_t)b * 25 + orow) * 64 + nt * 16 + l15] =
                __float2bfloat16(fmaxf(v, 0.f));
          } else {       // qkv ch 0..95 -> LDS (k already log2e-scaled via weights)
            qs[((nt - 2) * 16 + l15) * 28 + orow] = __float2bfloat16(v);
          }
        }
      }
    }
  }

  // ---- phase 2: attention, dkh=1; e = 2^(q * k*log2e) via raw v_exp_f32.
  //      PACKED inner loop: j in pairs via v_pk_mul/add/fma_f32 (full-rate fp32
  //      pairs on CDNA4); 4 packed + 1 scalar acc chains. ----
  {
    const int n = t & 31, half = t >> 5;
    const __bf16* qp = qs + n * 28;
    const __bf16* kp = qs + (32 + n) * 28;
    const __bf16* vp = qs + (64 + n) * 28;
    f32x2 kl2[12], vv2[12];
    float kl24, vv24;
#pragma unroll
    for (int c4 = 0; c4 < 6; ++c4) {
      bf16x4 bb = *(const bf16x4*)(kp + c4 * 4);
      bf16x4 cc = *(const bf16x4*)(vp + c4 * 4);
      kl2[c4 * 2]     = (f32x2){(float)bb[0], (float)bb[1]};
      kl2[c4 * 2 + 1] = (f32x2){(float)bb[2], (float)bb[3]};
      vv2[c4 * 2]     = (f32x2){(float)cc[0], (float)cc[1]};
      vv2[c4 * 2 + 1] = (f32x2){(float)cc[2], (float)cc[3]};
    }
    kl24 = (float)kp[24]; vv24 = (float)vp[24];

    const int i0 = half * 12;
    float qv[13];
    {
      const __bf16* qbase = qp + i0;  // row*56 + i0*2: 8B-aligned for i0 in {0,12}
      bf16x4 q0 = *(const bf16x4*)(qbase);
      bf16x4 q1 = *(const bf16x4*)(qbase + 4);
      bf16x4 q2 = *(const bf16x4*)(qbase + 8);
#pragma unroll
      for (int z = 0; z < 4; ++z) {
        qv[z] = (float)q0[z]; qv[4 + z] = (float)q1[z]; qv[8 + z] = (float)q2[z];
      }
      qv[12] = (float)qbase[12];
    }

#pragma unroll
    for (int z = 0; z < 13; ++z) {
      const float qi = qv[z];
      const f32x2 qi2 = {qi, qi};
      f32x2 sA = {0.f, 0.f}, sB = {0.f, 0.f};
      f32x2 oA = {0.f, 0.f}, oB = {0.f, 0.f};
      float s4 = 0.f, o4 = 0.f;
#pragma unroll
      for (int p = 0; p < 6; ++p) {
        f32x2 mA = qi2 * kl2[p];          // v_pk_mul_f32
        f32x2 mB = qi2 * kl2[p + 6];
        f32x2 eA = {fast_exp2(mA.x), fast_exp2(mA.y)};
        f32x2 eB = {fast_exp2(mB.x), fast_exp2(mB.y)};
        sA += eA;                          // v_pk_add_f32
        sB += eB;
        oA = eA * vv2[p] + oA;             // v_pk_fma_f32 (fp-contract)
        oB = eB * vv2[p + 6] + oB;
      }
      {
        float e = fast_exp2(qi * kl24);
        s4 += e;
        o4 = __builtin_fmaf(e, vv24, o4);
      }
      float ss = ((sA.x + sA.y) + (sB.x + sB.y)) + s4;
      float oo = ((oA.x + oA.y) + (oB.x + oB.y)) + o4;
      as_[(i0 + z) * 32 + n] = __float2bfloat16(oo * __builtin_amdgcn_rcpf(ss));
    }
  }

  // ---- phase 3: 1x1 conv via MFMA. M=25 rows, K=32 heads, N=32 ----
  {
    bf16x8 bw[2]; float ab[2];
#pragma unroll
    for (int nt2 = 0; nt2 < 2; ++nt2) {
      int n = nt2 * 16 + l15;
      bw[nt2] = *(const bf16x8*)((const __bf16*)wab + n * 32 + quad * 8);
      ab[nt2] = attn_b[n];
    }
#pragma unroll
    for (int mt = 0; mt < 2; ++mt) {
      int row = mt * 16 + l15;
      int rc = row < 24 ? row : 24;
      bf16x8 af = *(const bf16x8*)(as_ + rc * 32 + quad * 8);
      f32x4 acc[2];
#pragma unroll
      for (int nt2 = 0; nt2 < 2; ++nt2)
        acc[nt2] = mfma16(af, bw[nt2], (f32x4){0.f, 0.f, 0.f, 0.f});
#pragma unroll
      for (int r = 0; r < 4; ++r) {
        int orow = mt * 16 + quad * 4 + r;
        if (orow < 25) {
#pragma unroll
          for (int nt2 = 0; nt2 < 2; ++nt2)
            act[((size_t)b * 25 + orow) * 64 + 32 + nt2 * 16 + l15] =
                __float2bfloat16(fmaxf(acc[nt2][r] + ab[nt2], 0.f));
        }
      }
    }
  }
}

// ---------------- k2: fused dense chain — R2-proven 32-row/2-acc shape (unchanged) ----------------
__global__ __launch_bounds__(512) void k2(
    const __hip_bfloat16* __restrict__ act,
    const __hip_bfloat16* __restrict__ w1bp, const float* __restrict__ b1,
    const __hip_bfloat16* __restrict__ w2b, const float* __restrict__ b2,
    const float* __restrict__ w3, const float* __restrict__ b3,
    float* __restrict__ out) {
  const int t = threadIdx.x;
  const int lane = t & 63;
  const int wave = t >> 6;   // 0..7
  const int wm = wave >> 2;  // 0..1
  const int wn = wave & 3;   // 0..3
  const int l15 = lane & 15;
  const int quad = lane >> 4;  // 0..3
  const int b0 = blockIdx.x * 32;

  __shared__ __hip_bfloat16 C1s[32 * 136];
  __shared__ __hip_bfloat16 C2s[32 * 72];

  // ---- layer 1: [32,1600] x [128,1600]^T ----
  f32x4 acc0 = {0.f, 0.f, 0.f, 0.f};
  f32x4 acc1 = {0.f, 0.f, 0.f, 0.f};
  const __bf16* aptr  = (const __bf16*)act + (size_t)(b0 + wm * 16 + l15) * 1600 + quad * 8;
  const __bf16* bptr0 = (const __bf16*)w1bp + (size_t)(wn * 32 + l15) * 1600 + quad * 8;
  const __bf16* bptr1 = bptr0 + 16 * 1600;
#pragma unroll 5
  for (int k0 = 0; k0 < 1600; k0 += 32) {
    bf16x8 av  = *(const bf16x8*)(aptr + k0);
    bf16x8 bv0 = *(const bf16x8*)(bptr0 + k0);
    bf16x8 bv1 = *(const bf16x8*)(bptr1 + k0);
    acc0 = mfma16(av, bv0, acc0);
    acc1 = mfma16(av, bv1, acc1);
  }
  {
    const int col0 = wn * 32 + l15;
    const float bias0 = b1[col0];
    const float bias1 = b1[col0 + 16];
#pragma unroll
    for (int r = 0; r < 4; ++r) {
      const int row = wm * 16 + quad * 4 + r;
      C1s[row * 136 + col0]      = __float2bfloat16(fmaxf(acc0[r] + bias0, 0.f));
      C1s[row * 136 + col0 + 16] = __float2bfloat16(fmaxf(acc1[r] + bias1, 0.f));
    }
  }
  __syncthreads();

  // ---- layer 2: [32,128] x [64,128]^T ----
  f32x4 acc2 = {0.f, 0.f, 0.f, 0.f};
  {
    const __bf16* aL = (const __bf16*)C1s + (wm * 16 + l15) * 136 + quad * 8;
    const __bf16* bL = (const __bf16*)w2b + (wn * 16 + l15) * 128 + quad * 8;
#pragma unroll
    for (int k0 = 0; k0 < 128; k0 += 32)
      acc2 = mfma16(*(const bf16x8*)(aL + k0), *(const bf16x8*)(bL + k0), acc2);
  }
  {
    const int col = wn * 16 + l15;
    const float bias = b2[col];
#pragma unroll
    for (int r = 0; r < 4; ++r) {
      const int row = wm * 16 + quad * 4 + r;
      C2s[row * 72 + col] = __float2bfloat16(fmaxf(acc2[r] + bias, 0.f));
    }
  }
  __syncthreads();

  // ---- layer 3 (scalar, 160 outputs) ----
  if (t < 160) {
    const int row = t / 5;
    const int oc = t - row * 5;
    float s = b3[oc];
#pragma unroll
    for (int k = 0; k < 64; ++k)
      s += __bfloat162float(C2s[row * 72 + k]) * w3[oc * 64 + k];
    out[(size_t)(b0 + row) * 5 + oc] = s;
  }
}

extern "C" void kernel_launch(void* const* d_in, const int* in_sizes, int n_in,
                              void* d_out, int out_size, void* d_ws, size_t ws_size,
                              hipStream_t stream) {
  const float* x      = (const float*)d_in[0];
  const float* conv_w = (const float*)d_in[1];
  const float* conv_b = (const float*)d_in[2];
  const float* qkv_w  = (const float*)d_in[3];
  const float* qkv_b  = (const float*)d_in[4];
  const float* attn_w = (const float*)d_in[5];
  const float* attn_b = (const float*)d_in[6];
  const float* w1 = (const float*)d_in[7];
  const float* b1 = (const float*)d_in[8];
  const float* w2 = (const float*)d_in[9];
  const float* b2 = (const float*)d_in[10];
  const float* w3 = (const float*)d_in[11];
  const float* b3 = (const float*)d_in[12];
  float* out = (float*)d_out;

  // workspace layout (16B-aligned):
  //   act   [8192][25][64] bf16 : 26,214,400 B
  //   w1bp  [128][1600]    bf16 :    409,600 B  (written by k1 tail units 0..127)
  //   w2b   [64][128]      bf16 :     16,384 B  (written by k1 tail units 128..131)
  //   wqb   [128][64]      bf16 :     16,384 B  (k rows pre-scaled by log2e)
  //   biasb [128]          f32  :        512 B  (k entries pre-scaled by log2e)
  //   wab   [32][32]       bf16 :      2,048 B
  char* ws = (char*)d_ws;
  __hip_bfloat16* act   = (__hip_bfloat16*)ws;
  __hip_bfloat16* w1bp  = (__hip_bfloat16*)(ws + 26214400);
  __hip_bfloat16* w2b   = (__hip_bfloat16*)(ws + 26624000);
  __hip_bfloat16* wqb   = (__hip_bfloat16*)(ws + 26640384);
  float*          biasb = (float*)(ws + 26656768);
  __hip_bfloat16* wab   = (__hip_bfloat16*)(ws + 26657280);

  prep_small<<<dim3(17), dim3(64), 0, stream>>>(conv_w, conv_b, qkv_w, qkv_b, attn_w,
                                                wqb, biasb, wab);
  k1<<<dim3(4096 + 66), dim3(128), 0, stream>>>(x, biasb, wqb, wab, attn_b,
                                                w1, w2, act, w1bp, w2b);
  k2<<<dim3(256), dim3(512), 0, stream>>>(act, w1bp, b1, w2b, b2, w3, b3, out);
}